// Round 1
// baseline (1423.683 us; speedup 1.0000x reference)
//
#include <hip/hip_runtime.h>
#include <math.h>

#define NB 4
#define NCX 16
#define NC1 16
#define NCA 8
#define NN 1024
#define ND 64
#define NL 64

// ---------------------------------------------------------------------------
// K1: meanA[b,i,j] = (1/8) * sum_c A[b,c,i,j]
// Sequential channel order to match numpy's strided-axis reduce rounding.
// ---------------------------------------------------------------------------
__global__ __launch_bounds__(256) void k_meanA(const float* __restrict__ A,
                                               float* __restrict__ meanA) {
    int id = blockIdx.x * 256 + threadIdx.x;   // float4 index over B*N*N/4
    int b  = id >> 18;                         // N*N/4 = 262144
    int e  = id & 262143;
    const float4* A4 = (const float4*)A;
    float4 s = A4[(size_t)(b * NCA) * 262144 + e];
#pragma unroll
    for (int c = 1; c < NCA; ++c) {
        float4 v = A4[(size_t)(b * NCA + c) * 262144 + e];
        s.x += v.x; s.y += v.y; s.z += v.z; s.w += v.w;
    }
    s.x *= 0.125f; s.y *= 0.125f; s.z *= 0.125f; s.w *= 0.125f;
    ((float4*)meanA)[id] = s;
}

// ---------------------------------------------------------------------------
// K2: S_mean[b,i,j] = (1/16) sum_c softmax_j( x[b,c,i,:] . x[b,c,j,:] )
// Block = (i-tile of 16 rows, b). 256 threads: wave w handles rows 4w..4w+3,
// lane jg handles columns j = jg + 64*u, u in [0,16).
// ---------------------------------------------------------------------------
__global__ __launch_bounds__(256, 2) void k_smean(const float* __restrict__ x,
                                                  float* __restrict__ Smean) {
    __shared__ float xi[16][64];       // broadcast reads -> no pad needed
    __shared__ float xj[256][65];      // pad 65: conflict-free b32 reads
    const int t  = threadIdx.x;
    const int rg = t >> 6;             // wave id 0..3
    const int jg = t & 63;
    const int lr = t >> 4;             // staging row 0..15
    const int lc = t & 15;             // staging col4 0..15
    const int b  = blockIdx.y;
    const int i0 = blockIdx.x * 16;
    const int r4 = rg * 4;

    float acc[4][16];
#pragma unroll
    for (int s = 0; s < 4; ++s)
#pragma unroll
        for (int u = 0; u < 16; ++u) acc[s][u] = 0.f;

    for (int c = 0; c < NCX; ++c) {
        const float4* xc4 = (const float4*)(x + (size_t)(b * NCX + c) * NN * ND);
        float lg[4][16];
#pragma unroll
        for (int s = 0; s < 4; ++s)
#pragma unroll
            for (int u = 0; u < 16; ++u) lg[s][u] = 0.f;

        __syncthreads();   // protect xi/xj from previous iteration's readers
        // stage xi (16 x 64)
        {
            float4 v = xc4[(i0 + lr) * 16 + lc];
            *(float4*)&xi[lr][lc * 4] = v;
        }
#pragma unroll
        for (int ch = 0; ch < 4; ++ch) {
            if (ch) __syncthreads();
            // stage xj chunk: rows 256*ch .. 256*ch+255
#pragma unroll
            for (int rep = 0; rep < 16; ++rep) {
                int gr = ch * 256 + rep * 16 + lr;
                float4 v = xc4[gr * 16 + lc];
                int jl = rep * 16 + lr;
                xj[jl][lc * 4 + 0] = v.x;
                xj[jl][lc * 4 + 1] = v.y;
                xj[jl][lc * 4 + 2] = v.z;
                xj[jl][lc * 4 + 3] = v.w;
            }
            __syncthreads();
            // compute: 4 rows x 4 cols per thread for this chunk
#pragma unroll
            for (int k4 = 0; k4 < 16; ++k4) {
                const float4 xv[4] = {
                    *(const float4*)&xi[r4 + 0][k4 * 4],
                    *(const float4*)&xi[r4 + 1][k4 * 4],
                    *(const float4*)&xi[r4 + 2][k4 * 4],
                    *(const float4*)&xi[r4 + 3][k4 * 4]
                };
#pragma unroll
                for (int kk = 0; kk < 4; ++kk) {
                    const int k = k4 * 4 + kk;
                    const float a[4] = { xj[jg][k], xj[jg + 64][k],
                                         xj[jg + 128][k], xj[jg + 192][k] };
#pragma unroll
                    for (int s = 0; s < 4; ++s) {
                        const float xs = ((const float*)&xv[s])[kk];
#pragma unroll
                        for (int uu = 0; uu < 4; ++uu)
                            lg[s][ch * 4 + uu] = fmaf(xs, a[uu], lg[s][ch * 4 + uu]);
                    }
                }
            }
        }
        // softmax per row (row's 1024 logits live in this wave: 64 lanes x 16 u)
#pragma unroll
        for (int s = 0; s < 4; ++s) {
            float m = lg[s][0];
#pragma unroll
            for (int u = 1; u < 16; ++u) m = fmaxf(m, lg[s][u]);
#pragma unroll
            for (int off = 32; off; off >>= 1) m = fmaxf(m, __shfl_xor(m, off, 64));
            float sum = 0.f;
#pragma unroll
            for (int u = 0; u < 16; ++u) {
                float e = __expf(lg[s][u] - m);
                lg[s][u] = e;
                sum += e;
            }
#pragma unroll
            for (int off = 32; off; off >>= 1) sum += __shfl_xor(sum, off, 64);
            float r = 1.0f / sum;
#pragma unroll
            for (int u = 0; u < 16; ++u) acc[s][u] += lg[s][u] * r;
        }
    }
    // store S_mean (coalesced: lanes jg consecutive)
#pragma unroll
    for (int s = 0; s < 4; ++s) {
        int row = i0 + r4 + s;
        float* Sp = Smean + ((size_t)b * NN + row) * NN;
#pragma unroll
        for (int u = 0; u < 16; ++u) Sp[jg + 64 * u] = acc[s][u] * 0.0625f;
    }
}

// ---------------------------------------------------------------------------
// K3: mm = mask.mask^T row-block; A_out = meanA + 0.02*sigmoid(S*mm/sqrt(10));
//     per-row top-5 (tie -> lowest index) + gather mask rows + max.
// Block = (i-tile 16, c1, b). Same thread layout as K2.
// ---------------------------------------------------------------------------
__global__ __launch_bounds__(256, 2) void k_final(const float* __restrict__ mask,
                                                  const float* __restrict__ Smean,
                                                  const float* __restrict__ meanA,
                                                  float* __restrict__ Aout,
                                                  float* __restrict__ maskUpd) {
    __shared__ float mi[16][64];
    __shared__ float mj[256][65];
    const int t  = threadIdx.x;
    const int rg = t >> 6;
    const int jg = t & 63;
    const int lr = t >> 4;
    const int lc = t & 15;
    const int i0 = blockIdx.x * 16;
    const int c1 = blockIdx.y;
    const int b  = blockIdx.z;
    const int r4 = rg * 4;

    const float* mbase = mask + (size_t)(b * NC1 + c1) * NN * NL;
    const float4* mc4  = (const float4*)mbase;

    float lg[4][16];
#pragma unroll
    for (int s = 0; s < 4; ++s)
#pragma unroll
        for (int u = 0; u < 16; ++u) lg[s][u] = 0.f;

    // stage mi
    {
        float4 v = mc4[(i0 + lr) * 16 + lc];
        *(float4*)&mi[lr][lc * 4] = v;
    }
#pragma unroll
    for (int ch = 0; ch < 4; ++ch) {
        if (ch) __syncthreads();
#pragma unroll
        for (int rep = 0; rep < 16; ++rep) {
            int gr = ch * 256 + rep * 16 + lr;
            float4 v = mc4[gr * 16 + lc];
            int jl = rep * 16 + lr;
            mj[jl][lc * 4 + 0] = v.x;
            mj[jl][lc * 4 + 1] = v.y;
            mj[jl][lc * 4 + 2] = v.z;
            mj[jl][lc * 4 + 3] = v.w;
        }
        __syncthreads();
#pragma unroll
        for (int k4 = 0; k4 < 16; ++k4) {
            const float4 xv[4] = {
                *(const float4*)&mi[r4 + 0][k4 * 4],
                *(const float4*)&mi[r4 + 1][k4 * 4],
                *(const float4*)&mi[r4 + 2][k4 * 4],
                *(const float4*)&mi[r4 + 3][k4 * 4]
            };
#pragma unroll
            for (int kk = 0; kk < 4; ++kk) {
                const int k = k4 * 4 + kk;
                const float a[4] = { mj[jg][k], mj[jg + 64][k],
                                     mj[jg + 128][k], mj[jg + 192][k] };
#pragma unroll
                for (int s = 0; s < 4; ++s) {
                    const float xs = ((const float*)&xv[s])[kk];
#pragma unroll
                    for (int uu = 0; uu < 4; ++uu)
                        lg[s][ch * 4 + uu] = fmaf(xs, a[uu], lg[s][ch * 4 + uu]);
                }
            }
        }
    }

    // A_out = meanA + 0.02*sigmoid(S*mm/sqrt(10)); keep values in lg for top-k
#pragma unroll
    for (int s = 0; s < 4; ++s) {
        int row = i0 + r4 + s;
        const float* Sp = Smean + ((size_t)b * NN + row) * NN;
        const float* Mp = meanA + ((size_t)b * NN + row) * NN;
        float* Ap = Aout + ((size_t)(b * NC1 + c1) * NN + row) * NN;
#pragma unroll
        for (int u = 0; u < 16; ++u) {
            int j = jg + 64 * u;
            float Sv = Sp[j];
            float mA = Mp[j];
            float z  = Sv * lg[s][u] * 0.31622776601683794f;  // 1/sqrt(10)
            float w  = 1.0f / (1.0f + __expf(-z));
            float ao = mA + 0.02f * w;
            Ap[j] = ao;
            lg[s][u] = ao;
        }
    }

    // top-5 per row via 5-pass wave argmax (tie -> lowest index), then gather
#pragma unroll
    for (int s = 0; s < 4; ++s) {
        int row = i0 + r4 + s;
        int idxs[5];
#pragma unroll
        for (int p = 0; p < 5; ++p) {
            float bv = lg[s][0];
            int   bj = jg;
#pragma unroll
            for (int u = 1; u < 16; ++u) {
                float v = lg[s][u];
                int j = jg + 64 * u;
                if (v > bv) { bv = v; bj = j; }
            }
#pragma unroll
            for (int off = 32; off; off >>= 1) {
                float ov = __shfl_xor(bv, off, 64);
                int   oj = __shfl_xor(bj, off, 64);
                if (ov > bv || (ov == bv && oj < bj)) { bv = ov; bj = oj; }
            }
            idxs[p] = bj;
            // clear winner (register-friendly predicated writes)
            const bool mine = (bj & 63) == jg;
            const int  cu   = bj >> 6;
#pragma unroll
            for (int u = 0; u < 16; ++u)
                lg[s][u] = (mine && u == cu) ? -INFINITY : lg[s][u];
        }
        float mx = mbase[(size_t)idxs[0] * NL + jg];
#pragma unroll
        for (int p = 1; p < 5; ++p)
            mx = fmaxf(mx, mbase[(size_t)idxs[p] * NL + jg]);
        maskUpd[((size_t)(b * NC1 + c1) * NN + row) * NL + jg] = mx;
    }
}

// ---------------------------------------------------------------------------
extern "C" void kernel_launch(void* const* d_in, const int* in_sizes, int n_in,
                              void* d_out, int out_size, void* d_ws, size_t ws_size,
                              hipStream_t stream) {
    const float* x    = (const float*)d_in[0];
    const float* A    = (const float*)d_in[1];
    const float* mask = (const float*)d_in[2];
    float* out     = (float*)d_out;
    float* Aout    = out;                                   // (B,C1,N,N)
    float* maskUpd = out + (size_t)NB * NC1 * NN * NN;      // (B,C1,N,L)
    float* meanA   = (float*)d_ws;                          // (B,N,N) 16 MB
    float* Smean   = meanA + (size_t)NB * NN * NN;          // (B,N,N) 16 MB

    hipLaunchKernelGGL(k_meanA, dim3((NB * NN * NN / 4) / 256), dim3(256), 0, stream,
                       A, meanA);
    hipLaunchKernelGGL(k_smean, dim3(NN / 16, NB), dim3(256), 0, stream,
                       x, Smean);
    hipLaunchKernelGGL(k_final, dim3(NN / 16, NC1, NB), dim3(256), 0, stream,
                       mask, Smean, meanA, Aout, maskUpd);
}

// Round 2
// 892.253 us; speedup vs baseline: 1.5956x; 1.5956x over previous
//
#include <hip/hip_runtime.h>
#include <math.h>

#define NB 4
#define NCX 16
#define NC1 16
#define NCA 8
#define NN 1024
#define ND 64
#define NL 64

// ---------------------------------------------------------------------------
// K1: meanA[b,i,j] = (1/8) * sum_c A[b,c,i,j]  (sequential channel order)
// ---------------------------------------------------------------------------
__global__ __launch_bounds__(256) void k_meanA(const float* __restrict__ A,
                                               float* __restrict__ meanA) {
    int id = blockIdx.x * 256 + threadIdx.x;   // float4 index over B*N*N/4
    int b  = id >> 18;                         // N*N/4 = 262144
    int e  = id & 262143;
    const float4* A4 = (const float4*)A;
    float4 s = A4[(size_t)(b * NCA) * 262144 + e];
#pragma unroll
    for (int c = 1; c < NCA; ++c) {
        float4 v = A4[(size_t)(b * NCA + c) * 262144 + e];
        s.x += v.x; s.y += v.y; s.z += v.z; s.w += v.w;
    }
    s.x *= 0.125f; s.y *= 0.125f; s.z *= 0.125f; s.w *= 0.125f;
    ((float4*)meanA)[id] = s;
}

// ---------------------------------------------------------------------------
// K2: per-channel softmax rows -> Spart[b,c,i,j] = softmax_j(x_i . x_j)
// Block = (i-tile 16, c, b); 4096 blocks, 4 blocks/CU (37 KB LDS).
// Wave rg handles rows r4..r4+3; lane jg covers j = 64u + jg, u = 2*ch + v.
// ---------------------------------------------------------------------------
__global__ __launch_bounds__(256, 4) void k_smean(const float* __restrict__ x,
                                                  float* __restrict__ Spart) {
    __shared__ float xi[16][64];       // broadcast reads
    __shared__ float xj[128][65];      // pad 65: 2-way (free) b32 reads
    const int t  = threadIdx.x;
    const int rg = t >> 6;
    const int jg = t & 63;
    const int lr = t >> 4;
    const int lc = t & 15;
    const int i0 = blockIdx.x * 16;
    const int c  = blockIdx.y;
    const int b  = blockIdx.z;
    const int r4 = rg * 4;

    const float4* xc4 = (const float4*)(x + (size_t)(b * NCX + c) * NN * ND);

    float lg[4][16];
#pragma unroll
    for (int s = 0; s < 4; ++s)
#pragma unroll
        for (int u = 0; u < 16; ++u) lg[s][u] = 0.f;

    // stage xi (16 x 64)
    *(float4*)&xi[lr][lc * 4] = xc4[(i0 + lr) * 16 + lc];

#pragma unroll
    for (int ch = 0; ch < 8; ++ch) {
        __syncthreads();               // xi visible (ch=0); xj reuse safe (ch>0)
#pragma unroll
        for (int rep = 0; rep < 8; ++rep) {
            int gr = ch * 128 + rep * 16 + lr;
            float4 v = xc4[gr * 16 + lc];
            int jl = rep * 16 + lr;
            xj[jl][lc * 4 + 0] = v.x;
            xj[jl][lc * 4 + 1] = v.y;
            xj[jl][lc * 4 + 2] = v.z;
            xj[jl][lc * 4 + 3] = v.w;
        }
        __syncthreads();
#pragma unroll
        for (int k4 = 0; k4 < 16; ++k4) {
            const float4 xv0 = *(const float4*)&xi[r4 + 0][k4 * 4];
            const float4 xv1 = *(const float4*)&xi[r4 + 1][k4 * 4];
            const float4 xv2 = *(const float4*)&xi[r4 + 2][k4 * 4];
            const float4 xv3 = *(const float4*)&xi[r4 + 3][k4 * 4];
#pragma unroll
            for (int v = 0; v < 2; ++v) {
                const float* xr = &xj[jg + 64 * v][k4 * 4];
                const float a0 = xr[0], a1 = xr[1], a2 = xr[2], a3 = xr[3];
                const int u = ch * 2 + v;
                lg[0][u] = fmaf(xv0.x, a0, lg[0][u]);
                lg[0][u] = fmaf(xv0.y, a1, lg[0][u]);
                lg[0][u] = fmaf(xv0.z, a2, lg[0][u]);
                lg[0][u] = fmaf(xv0.w, a3, lg[0][u]);
                lg[1][u] = fmaf(xv1.x, a0, lg[1][u]);
                lg[1][u] = fmaf(xv1.y, a1, lg[1][u]);
                lg[1][u] = fmaf(xv1.z, a2, lg[1][u]);
                lg[1][u] = fmaf(xv1.w, a3, lg[1][u]);
                lg[2][u] = fmaf(xv2.x, a0, lg[2][u]);
                lg[2][u] = fmaf(xv2.y, a1, lg[2][u]);
                lg[2][u] = fmaf(xv2.z, a2, lg[2][u]);
                lg[2][u] = fmaf(xv2.w, a3, lg[2][u]);
                lg[3][u] = fmaf(xv3.x, a0, lg[3][u]);
                lg[3][u] = fmaf(xv3.y, a1, lg[3][u]);
                lg[3][u] = fmaf(xv3.z, a2, lg[3][u]);
                lg[3][u] = fmaf(xv3.w, a3, lg[3][u]);
            }
        }
    }
    // softmax per row, store per-channel result (reduce kernel sums channels)
#pragma unroll
    for (int s = 0; s < 4; ++s) {
        float m = lg[s][0];
#pragma unroll
        for (int u = 1; u < 16; ++u) m = fmaxf(m, lg[s][u]);
#pragma unroll
        for (int off = 32; off; off >>= 1) m = fmaxf(m, __shfl_xor(m, off, 64));
        float sum = 0.f;
#pragma unroll
        for (int u = 0; u < 16; ++u) {
            float e = __expf(lg[s][u] - m);
            lg[s][u] = e;
            sum += e;
        }
#pragma unroll
        for (int off = 32; off; off >>= 1) sum += __shfl_xor(sum, off, 64);
        float r = 1.0f / sum;
        int row = i0 + r4 + s;
        float* Sp = Spart + ((size_t)(b * NCX + c) * NN + row) * NN;
#pragma unroll
        for (int u = 0; u < 16; ++u) Sp[jg + 64 * u] = lg[s][u] * r;
    }
}

// ---------------------------------------------------------------------------
// K2b: Smean = (1/16) * sum_c Spart  (sequential channel order, bit-exact R1)
// ---------------------------------------------------------------------------
__global__ __launch_bounds__(256) void k_sreduce(const float* __restrict__ Spart,
                                                 float* __restrict__ Smean) {
    int id = blockIdx.x * 256 + threadIdx.x;   // float4 index over B*N*N/4
    int b  = id >> 18;
    int e  = id & 262143;
    const float4* S4 = (const float4*)Spart;
    float4 s = S4[(size_t)(b * NCX) * 262144 + e];
#pragma unroll
    for (int c = 1; c < NCX; ++c) {
        float4 v = S4[(size_t)(b * NCX + c) * 262144 + e];
        s.x += v.x; s.y += v.y; s.z += v.z; s.w += v.w;
    }
    s.x *= 0.0625f; s.y *= 0.0625f; s.z *= 0.0625f; s.w *= 0.0625f;
    ((float4*)Smean)[id] = s;
}

// ---------------------------------------------------------------------------
// K3: mm = mask.mask^T; A_out = meanA + 0.02*sigmoid(S*mm/sqrt(10));
//     per-row top-5 (tie -> lowest index) + gather mask rows + max.
// Block = (i-tile 16, c1, b); 128-row mj chunks -> 37 KB LDS, 4 blocks/CU.
// ---------------------------------------------------------------------------
__global__ __launch_bounds__(256, 4) void k_final(const float* __restrict__ mask,
                                                  const float* __restrict__ Smean,
                                                  const float* __restrict__ meanA,
                                                  float* __restrict__ Aout,
                                                  float* __restrict__ maskUpd) {
    __shared__ float mi[16][64];
    __shared__ float mj[128][65];
    const int t  = threadIdx.x;
    const int rg = t >> 6;
    const int jg = t & 63;
    const int lr = t >> 4;
    const int lc = t & 15;
    const int i0 = blockIdx.x * 16;
    const int c1 = blockIdx.y;
    const int b  = blockIdx.z;
    const int r4 = rg * 4;

    const float* mbase = mask + (size_t)(b * NC1 + c1) * NN * NL;
    const float4* mc4  = (const float4*)mbase;

    float lg[4][16];
#pragma unroll
    for (int s = 0; s < 4; ++s)
#pragma unroll
        for (int u = 0; u < 16; ++u) lg[s][u] = 0.f;

    *(float4*)&mi[lr][lc * 4] = mc4[(i0 + lr) * 16 + lc];

#pragma unroll
    for (int ch = 0; ch < 8; ++ch) {
        __syncthreads();
#pragma unroll
        for (int rep = 0; rep < 8; ++rep) {
            int gr = ch * 128 + rep * 16 + lr;
            float4 v = mc4[gr * 16 + lc];
            int jl = rep * 16 + lr;
            mj[jl][lc * 4 + 0] = v.x;
            mj[jl][lc * 4 + 1] = v.y;
            mj[jl][lc * 4 + 2] = v.z;
            mj[jl][lc * 4 + 3] = v.w;
        }
        __syncthreads();
#pragma unroll
        for (int k4 = 0; k4 < 16; ++k4) {
            const float4 xv0 = *(const float4*)&mi[r4 + 0][k4 * 4];
            const float4 xv1 = *(const float4*)&mi[r4 + 1][k4 * 4];
            const float4 xv2 = *(const float4*)&mi[r4 + 2][k4 * 4];
            const float4 xv3 = *(const float4*)&mi[r4 + 3][k4 * 4];
#pragma unroll
            for (int v = 0; v < 2; ++v) {
                const float* xr = &mj[jg + 64 * v][k4 * 4];
                const float a0 = xr[0], a1 = xr[1], a2 = xr[2], a3 = xr[3];
                const int u = ch * 2 + v;
                lg[0][u] = fmaf(xv0.x, a0, lg[0][u]);
                lg[0][u] = fmaf(xv0.y, a1, lg[0][u]);
                lg[0][u] = fmaf(xv0.z, a2, lg[0][u]);
                lg[0][u] = fmaf(xv0.w, a3, lg[0][u]);
                lg[1][u] = fmaf(xv1.x, a0, lg[1][u]);
                lg[1][u] = fmaf(xv1.y, a1, lg[1][u]);
                lg[1][u] = fmaf(xv1.z, a2, lg[1][u]);
                lg[1][u] = fmaf(xv1.w, a3, lg[1][u]);
                lg[2][u] = fmaf(xv2.x, a0, lg[2][u]);
                lg[2][u] = fmaf(xv2.y, a1, lg[2][u]);
                lg[2][u] = fmaf(xv2.z, a2, lg[2][u]);
                lg[2][u] = fmaf(xv2.w, a3, lg[2][u]);
                lg[3][u] = fmaf(xv3.x, a0, lg[3][u]);
                lg[3][u] = fmaf(xv3.y, a1, lg[3][u]);
                lg[3][u] = fmaf(xv3.z, a2, lg[3][u]);
                lg[3][u] = fmaf(xv3.w, a3, lg[3][u]);
            }
        }
    }

    // A_out = meanA + 0.02*sigmoid(S*mm/sqrt(10)); keep values in lg for top-k
#pragma unroll
    for (int s = 0; s < 4; ++s) {
        int row = i0 + r4 + s;
        const float* Sp = Smean + ((size_t)b * NN + row) * NN;
        const float* Mp = meanA + ((size_t)b * NN + row) * NN;
        float* Ap = Aout + ((size_t)(b * NC1 + c1) * NN + row) * NN;
#pragma unroll
        for (int u = 0; u < 16; ++u) {
            int j = jg + 64 * u;
            float Sv = Sp[j];
            float mA = Mp[j];
            float z  = Sv * lg[s][u] * 0.31622776601683794f;  // 1/sqrt(10)
            float w  = 1.0f / (1.0f + __expf(-z));
            float ao = mA + 0.02f * w;
            Ap[j] = ao;
            lg[s][u] = ao;
        }
    }

    // top-5 per row via 5-pass wave argmax (tie -> lowest index), then gather
#pragma unroll
    for (int s = 0; s < 4; ++s) {
        int row = i0 + r4 + s;
        int idxs[5];
#pragma unroll
        for (int p = 0; p < 5; ++p) {
            float bv = lg[s][0];
            int   bj = jg;
#pragma unroll
            for (int u = 1; u < 16; ++u) {
                float v = lg[s][u];
                int j = jg + 64 * u;
                if (v > bv) { bv = v; bj = j; }
            }
#pragma unroll
            for (int off = 32; off; off >>= 1) {
                float ov = __shfl_xor(bv, off, 64);
                int   oj = __shfl_xor(bj, off, 64);
                if (ov > bv || (ov == bv && oj < bj)) { bv = ov; bj = oj; }
            }
            idxs[p] = bj;
            const bool mine = (bj & 63) == jg;
            const int  cu   = bj >> 6;
#pragma unroll
            for (int u = 0; u < 16; ++u)
                lg[s][u] = (mine && u == cu) ? -INFINITY : lg[s][u];
        }
        float mx = mbase[(size_t)idxs[0] * NL + jg];
#pragma unroll
        for (int p = 1; p < 5; ++p)
            mx = fmaxf(mx, mbase[(size_t)idxs[p] * NL + jg]);
        maskUpd[((size_t)(b * NC1 + c1) * NN + row) * NL + jg] = mx;
    }
}

// ---------------------------------------------------------------------------
extern "C" void kernel_launch(void* const* d_in, const int* in_sizes, int n_in,
                              void* d_out, int out_size, void* d_ws, size_t ws_size,
                              hipStream_t stream) {
    const float* x    = (const float*)d_in[0];
    const float* A    = (const float*)d_in[1];
    const float* mask = (const float*)d_in[2];
    float* out     = (float*)d_out;
    float* Aout    = out;                                   // (B,C1,N,N)
    float* maskUpd = out + (size_t)NB * NC1 * NN * NN;      // (B,C1,N,L)
    float* meanA   = (float*)d_ws;                          // (B,N,N) 16 MB
    float* Smean   = meanA + (size_t)NB * NN * NN;          // (B,N,N) 16 MB
    float* Spart   = Aout;   // (B,Cx,N,N) 268 MB scratch inside d_out, consumed
                             // by k_sreduce before k_final overwrites it.

    hipLaunchKernelGGL(k_meanA, dim3((NB * NN * NN / 4) / 256), dim3(256), 0, stream,
                       A, meanA);
    hipLaunchKernelGGL(k_smean, dim3(NN / 16, NCX, NB), dim3(256), 0, stream,
                       x, Spart);
    hipLaunchKernelGGL(k_sreduce, dim3((NB * NN * NN / 4) / 256), dim3(256), 0, stream,
                       Spart, Smean);
    hipLaunchKernelGGL(k_final, dim3(NN / 16, NC1, NB), dim3(256), 0, stream,
                       mask, Smean, meanA, Aout, maskUpd);
}